// Round 6
// baseline (386.019 us; speedup 1.0000x reference)
//
#include <hip/hip_runtime.h>

// Problem constants
#define HW    128
#define NCELL 16
#define ABUF_PER_CELL 46080     // 5 chunks * 3 kh * 2 splits * 4 quads * 48 co * 8

typedef _Float16 half8 __attribute__((ext_vector_type(8)));
typedef float    f32x4 __attribute__((ext_vector_type(4)));

// 16B-granular XOR swizzle (permutes within 8-unit groups; involution)
__device__ __forceinline__ int swz(int u) { return u ^ ((u >> 3) & 7); }

// ---------------------------------------------------------------------------
// Weight prep: W[cell][co][ci][kh][kw] fp32 -> A-fragment-ordered fp16 hi/lo.
// Abuf: [cell][chunk5][kh3][split2][quad4][co48][j8] halfs; k = chunk*32 +
// quad*8 + j indexes the per-kh K-run (k = kw*48 + ci; 144 valid, rest 0).
// (Validated rounds 2-5.)
// ---------------------------------------------------------------------------
__global__ void prep_w_k(const float* __restrict__ W, _Float16* __restrict__ Abuf) {
    int idx = blockIdx.x * 256 + threadIdx.x;
    if (idx >= NCELL * ABUF_PER_CELL) return;
    int j = idx & 7;
    int t = idx >> 3;
    int co = t % 48;  t /= 48;
    int quad = t & 3; t >>= 2;
    int s = t & 1;    t >>= 1;
    int kh = t % 3;   t /= 3;
    int chunk = t % 5; t /= 5;
    int cell = t;
    int k = chunk * 32 + quad * 8 + j;
    float v = 0.f;
    if (k < 144) {
        int kw = k / 48, ci = k - kw * 48;
        v = W[((size_t)(cell * 48 + co) * 48 + ci) * 9 + kh * 3 + kw];
    }
    _Float16 h = (_Float16)v;
    if (s == 1) h = (_Float16)(v - (float)h);
    Abuf[idx] = h;
}

// Per-cell I/O descriptor (fp32 NCHW streams, round-4 proven format)
struct CellIO {
    const float* in0; const float* in1; const float* in2;
    const _Float16* Ac; const float* bc;
    float* o0; float* o1; float* o2;
};

// ---------------------------------------------------------------------------
// One grid-cell conv body, implicit GEMM on MFMA (fp16x3 = fp32 accuracy).
// LIVE: compile-time mask of live output streams (1=right,2=up,4=down).
// NIN : compile-time number of live input slots.
// Block: 512 thr = 8 waves on a 16x16 px tile (wave w: rows 2w..2w+1).
// 2 blocks/CU (62.5 KB LDS) x 8 waves = 4 waves/SIMD for latency hiding.
// ---------------------------------------------------------------------------
template<int LIVE, int NIN>
__device__ __forceinline__ void cell_body(const CellIO& P, int b,
                                          _Float16* xh, _Float16* xl)
{
    const int tid = threadIdx.x;
    const int x0 = blockIdx.x * 16, y0 = blockIdx.y * 16;

    // Zero the swizzle-overread tail (units 1944..1951): chunk-4 k in
    // [144,160) B-reads touch these; A is zero there but 0*NaN = NaN.
    if (tid < 64) { xh[15552 + tid] = (_Float16)0.f; xl[15552 + tid] = (_Float16)0.f; }

    // ---- stage 48ch x 18x18 halo: 864 row-tasks (ci, iy); fp32 NCHW ->
    //      h/l split, channel-last (pixel stride 48), 16B-swizzled ----
    for (int task = tid; task < 864; task += 512) {
        int ci = task / 18, iy = task - ci * 18;
        float v[18];
#pragma unroll
        for (int ix = 0; ix < 18; ++ix) v[ix] = 0.f;
        if (ci < NIN * 16) {                              // compile-time prune
            const float* p = (ci < 16) ? P.in0 : (ci < 32 ? P.in1 : P.in2);
            int gy = y0 + iy - 1;
            if ((unsigned)gy < (unsigned)HW) {
                const float* rp = p + (((size_t)b * 16 + (ci & 15)) * HW + gy) * HW + x0;
                f32x4 q0 = *(const f32x4*)(rp);
                f32x4 q1 = *(const f32x4*)(rp + 4);
                f32x4 q2 = *(const f32x4*)(rp + 8);
                f32x4 q3 = *(const f32x4*)(rp + 12);
#pragma unroll
                for (int j = 0; j < 4; ++j) {
                    v[1 + j] = q0[j]; v[5 + j] = q1[j];
                    v[9 + j] = q2[j]; v[13 + j] = q3[j];
                }
                if (x0 > 0)       v[0]  = rp[-1];
                if (x0 < HW - 16) v[17] = rp[16];
            }
        }
#pragma unroll
        for (int ix = 0; ix < 18; ++ix) {
            float fv = v[ix];
            _Float16 h = (_Float16)fv;
            _Float16 l = (_Float16)(fv - (float)h);
            int a = (iy * 18 + ix) * 48 + ci;
            int as = swz(a >> 3) * 8 + (a & 7);
            xh[as] = h; xl[as] = l;
        }
    }
    __syncthreads();

    const int lane = tid & 63, wv = tid >> 6;     // wv in 0..7
    const int n = lane & 15, quad = lane >> 4;
    const int py0 = wv * 2;                       // 2 output rows per wave

    // acc[cot][nt]: D tile, co = cot*16 + quad*4 + r, pixel (y0+py0+nt, x0+n)
    f32x4 acc[3][2];
#pragma unroll
    for (int cot = 0; cot < 3; ++cot) {
        if (!(LIVE & (1 << cot))) continue;
#pragma unroll
        for (int r = 0; r < 4; ++r) {
            float bv = P.bc[cot * 16 + quad * 4 + r];
#pragma unroll
            for (int nt = 0; nt < 2; ++nt) acc[cot][nt][r] = bv;
        }
    }

    // ---- K loop: 5 chunks x 3 kh over the per-kh (kw,ci) run, branch-free.
    //      4 waves/SIMD provide the latency hiding; loads inline. ----
    const _Float16* Abase = P.Ac + quad * 384 + n * 8;
#pragma unroll
    for (int chunk = 0; chunk < 5; ++chunk) {
        half8 Bh[4], Bl[4];
#pragma unroll
        for (int r = 0; r < 4; ++r) {             // rows py0 .. py0+3
            int a = ((py0 + r) * 18 + n) * 48 + chunk * 32 + quad * 8;
            int u = swz(a >> 3) * 8;
            Bh[r] = *(const half8*)(xh + u);
            Bl[r] = *(const half8*)(xl + u);
        }
#pragma unroll
        for (int kh = 0; kh < 3; ++kh) {
            const _Float16* Ab = Abase + (size_t)((chunk * 3 + kh) * 2) * 1536;
#pragma unroll
            for (int cot = 0; cot < 3; ++cot) {
                if (!(LIVE & (1 << cot))) continue;   // compile-time
                half8 ah = *(const half8*)(Ab + cot * 128);
                half8 al = *(const half8*)(Ab + 1536 + cot * 128);
#pragma unroll
                for (int nt = 0; nt < 2; ++nt) {
                    acc[cot][nt] = __builtin_amdgcn_mfma_f32_16x16x32_f16(ah, Bh[nt + kh], acc[cot][nt], 0, 0, 0);
                    acc[cot][nt] = __builtin_amdgcn_mfma_f32_16x16x32_f16(al, Bh[nt + kh], acc[cot][nt], 0, 0, 0);
                    acc[cot][nt] = __builtin_amdgcn_mfma_f32_16x16x32_f16(ah, Bl[nt + kh], acc[cot][nt], 0, 0, 0);
                }
            }
        }
    }

    // ---- epilogue: ReLU + direct fp32 NCHW stores (round-4 proven) ----
    float* const outs[3] = {P.o0, P.o1, P.o2};
#pragma unroll
    for (int cot = 0; cot < 3; ++cot) {
        if (!(LIVE & (1 << cot))) continue;
        float* op = outs[cot];
#pragma unroll
        for (int nt = 0; nt < 2; ++nt) {
            int y = y0 + py0 + nt, xg = x0 + n;
#pragma unroll
            for (int r = 0; r < 4; ++r) {
                float vv = acc[cot][nt][r];
                op[(((size_t)b * 16 + quad * 4 + r) * HW + y) * HW + xg] = vv > 0.f ? vv : 0.f;
            }
        }
    }
}

// ---------------------------------------------------------------------------
// Stage kernel: one or two independent cells per launch. blockIdx.z < 8 ->
// cell 0 (batch z), z >= 8 -> cell 1 (batch z-8). L1==0 -> single-cell.
// ---------------------------------------------------------------------------
template<int L0, int N0, int L1, int N1>
__global__ __launch_bounds__(512, 4) void cell_k(CellIO P0, CellIO P1) {
    __shared__ __align__(16) _Float16 xh[15616];
    __shared__ __align__(16) _Float16 xl[15616];
    int b = blockIdx.z & 7;
    if constexpr (L1 > 0) {
        if (blockIdx.z >= 8) { cell_body<L1, N1>(P1, b, xh, xl); return; }
    }
    cell_body<L0, N0>(P0, b, xh, xl);
}

// ---------------------------------------------------------------------------
// Orchestration: anti-diagonal stage schedule s = 2*col + row; cells within a
// stage are independent (deps land at s-1 / s-2; validated round 5).
// Buffers: R[colpar][row] x8, U[1..3] x3, D[colpar][rowpar] x4 (pair mode) or
// D aliased to 2 (sequential fallback if ws too small = round-4 scheme).
// ---------------------------------------------------------------------------
extern "C" void kernel_launch(void* const* d_in, const int* in_sizes, int n_in,
                              void* d_out, int out_size, void* d_ws, size_t ws_size,
                              hipStream_t stream) {
    const float* x  = (const float*)d_in[0];   // [8,16,128,128]
    const float* W  = (const float*)d_in[1];   // [4,4,48,48,3,3]
    const float* bi = (const float*)d_in[2];   // [4,4,48]
    float* out = (float*)d_out;                // [8,16,128,128]

    _Float16* Abuf = (_Float16*)d_ws;
    const size_t abytes = (size_t)NCELL * ABUF_PER_CELL * 2;   // 1.47 MB
    float* q = (float*)((char*)d_ws + abytes);
    const size_t S = (size_t)8 * 16 * HW * HW;                 // floats/buffer

    const bool pair_ok = ws_size >= abytes + (size_t)15 * S * 4;

    float *R[2][4], *U[4], *D[2][2];
    for (int pa = 0; pa < 2; ++pa)
        for (int r = 0; r < 4; ++r) { R[pa][r] = q; q += S; }
    U[0] = nullptr;
    for (int r = 1; r < 4; ++r) { U[r] = q; q += S; }
    D[0][0] = q; q += S; D[0][1] = q; q += S;
    if (pair_ok) { D[1][0] = q; q += S; D[1][1] = q; q += S; }
    else         { D[1][0] = D[0][0];   D[1][1] = D[0][1]; }   // round-4 alias

    hipLaunchKernelGGL(prep_w_k, dim3((NCELL * ABUF_PER_CELL + 255) / 256),
                       dim3(256), 0, stream, W, Abuf);

    auto mkio = [&](int c, int r) -> CellIO {
        CellIO io{};
        if (c == 0) {
            io.in0 = (r == 0) ? x : D[0][(r - 1) & 1];
        } else {
            io.in0 = R[(c - 1) & 1][r];
            if (r == 0)      io.in1 = U[1];
            else if (r == 3) io.in1 = D[c & 1][0];
            else { io.in1 = U[r + 1]; io.in2 = D[c & 1][(r - 1) & 1]; }
        }
        if (c < 3) {
            io.o0 = R[c & 1][r];
            if (r > 0) io.o1 = U[r];
            if (r < 3) io.o2 = D[c & 1][r & 1];
        } else {
            if (r < 3) io.o2 = D[1][r & 1];
            else       io.o0 = out;
        }
        io.Ac = Abuf + (size_t)(c * 4 + r) * ABUF_PER_CELL;
        io.bc = bi + (size_t)(c * 4 + r) * 48;
        return io;
    };

    dim3 blk(512), g1(8, 8, 8), g2(8, 8, 16);
#define ONE(L, N, c, r)  do { CellIO a = mkio(c, r); \
    hipLaunchKernelGGL((cell_k<L, N, 0, 0>), g1, blk, 0, stream, a, a); } while (0)
#define TWO(L0, N0, c0, r0, L1, N1, c1, r1) do { \
    CellIO a = mkio(c0, r0), bb2 = mkio(c1, r1); \
    hipLaunchKernelGGL((cell_k<L0, N0, L1, N1>), g2, blk, 0, stream, a, bb2); } while (0)
#define ONEP(L0, N0, c, r, L1, N1) do { CellIO a = mkio(c, r); \
    hipLaunchKernelGGL((cell_k<L0, N0, L1, N1>), g1, blk, 0, stream, a, a); } while (0)

    if (pair_ok) {
        ONE(5, 1, 0, 0);
        ONE(7, 1, 0, 1);
        TWO(7, 1, 0, 2,  5, 2, 1, 0);
        TWO(3, 1, 0, 3,  7, 3, 1, 1);
        TWO(7, 3, 1, 2,  5, 2, 2, 0);
        TWO(3, 2, 1, 3,  7, 3, 2, 1);
        TWO(7, 3, 2, 2,  4, 2, 3, 0);
        TWO(3, 2, 2, 3,  4, 3, 3, 1);
        ONE(4, 3, 3, 2);
        ONE(1, 2, 3, 3);
    } else {
        // Sequential col-major fallback (round-4 proven order); pair kernels
        // with g1 so only P0 executes.
        ONE(5, 1, 0, 0);
        ONE(7, 1, 0, 1);
        ONEP(7, 1, 0, 2, 5, 2);
        ONEP(3, 1, 0, 3, 7, 3);
        ONEP(5, 2, 1, 0, 0, 0);
        ONEP(7, 3, 1, 1, 0, 0);
        ONEP(7, 3, 1, 2, 0, 0);
        ONEP(3, 2, 1, 3, 7, 3);
        ONEP(5, 2, 2, 0, 0, 0);
        ONEP(7, 3, 2, 1, 0, 0);
        ONEP(7, 3, 2, 2, 4, 2);
        ONEP(3, 2, 2, 3, 4, 3);
        ONEP(4, 2, 3, 0, 0, 0);
        ONEP(4, 3, 3, 1, 0, 0);
        ONE(4, 3, 3, 2);
        ONE(1, 2, 3, 3);
    }
#undef ONE
#undef TWO
#undef ONEP
}